// Round 1
// baseline (425.163 us; speedup 1.0000x reference)
//
#include <hip/hip_runtime.h>
#include <hip/hip_bf16.h>

typedef __attribute__((ext_vector_type(8))) short short8;
typedef __attribute__((ext_vector_type(4))) float f32x4;

constexpr int T    = 60;    // driven timesteps
constexpr int C    = 128;   // channels == hidden
constexpr int NPIX = 4096;  // samples
constexpr int H    = 128;
constexpr int GP   = 5;
constexpr int EXTRA = T - GP - 1;   // 54 autoregressive steps
constexpr int TT    = T + EXTRA;    // 114 total outputs
constexpr int LDS_STRIDE = 136;     // bf16 elems/row: 272 B, 16B-aligned, breaks pow2 banks

__device__ __forceinline__ unsigned short f2bf(float f) {
  unsigned u = __float_as_uint(f);
  u += 0x7FFF + ((u >> 16) & 1);   // round-to-nearest-even
  return (unsigned short)(u >> 16);
}
__device__ __forceinline__ float bf2f(unsigned short s) {
  return __uint_as_float(((unsigned)s) << 16);
}
__device__ __forceinline__ float fast_sigmoid(float x) {
  float e = __builtin_amdgcn_exp2f(-1.44269504f * x);
  return __builtin_amdgcn_rcpf(1.0f + e);
}
__device__ __forceinline__ float fast_tanh(float x) {
  float e = __builtin_amdgcn_exp2f(2.88539008f * x);   // exp(2x)
  return 1.0f - 2.0f * __builtin_amdgcn_rcpf(1.0f + e);
}

// One WG owns 16 samples and runs all 114 steps. 8 waves; wave w owns gate
// columns {nt*128 + 16w .. +15} for nt=0..3 (i,f,g,o) -> each lane holds all
// 4 gates of its (sample, hidden) pairs after MFMA (C layout: col=lane&15,
// row=quad*4+r). Weights live in VGPRs as bf16 B-fragments.
__global__ __launch_bounds__(512, 2) void lstm_persistent(
    const float* __restrict__ img,   // [T][C][NPIX]
    const float* __restrict__ wih,   // [4H][C]
    const float* __restrict__ whh,   // [4H][H]
    const float* __restrict__ bih,
    const float* __restrict__ bhh,
    float* __restrict__ out)         // [NPIX][TT][H]
{
  __shared__ __align__(16) unsigned short xs[16 * LDS_STRIDE];
  __shared__ __align__(16) unsigned short hs[16 * LDS_STRIDE];

  const int tid  = threadIdx.x;
  const int lane = tid & 63;
  const int w    = tid >> 6;      // wave 0..7
  const int l15  = lane & 15;
  const int quad = lane >> 4;     // 0..3
  const int n0   = blockIdx.x * 16;
  const int hid  = w * 16 + l15;  // hidden column this lane owns

  // ---- load weight fragments (B-operand layout: lane holds B[k=quad*8+j][n=l15],
  // B[k][n] = W[col][k] -> 8 consecutive k from one W row) ----
  short8 fih[4][4], fhh[4][4];
  float bias[4];
  #pragma unroll
  for (int nt = 0; nt < 4; ++nt) {
    const int col = nt * 128 + hid;
    bias[nt] = bih[col] + bhh[col];
    #pragma unroll
    for (int kt = 0; kt < 4; ++kt) {
      const int k0 = kt * 32 + quad * 8;
      const float* pih = wih + col * C + k0;
      const float* phh = whh + col * C + k0;
      short8 a, b;
      #pragma unroll
      for (int j = 0; j < 8; ++j) {
        a[j] = (short)f2bf(pih[j]);
        b[j] = (short)f2bf(phh[j]);
      }
      fih[nt][kt] = a;
      fhh[nt][kt] = b;
    }
  }

  // zero h state in LDS
  for (int i = tid; i < 16 * LDS_STRIDE; i += 512) hs[i] = 0;

  // fp32 cell state: lane owns (sample = quad*4 + r, hid) for r=0..3
  float c[4] = {0.f, 0.f, 0.f, 0.f};

  // x staging: thread covers (nl = tid&15, channels cb..cb+3)
  const int nl = tid & 15;
  const int cb = (tid >> 4) * 4;
  const float* xbase = img + (size_t)cb * NPIX + n0 + nl;  // +NPIX per channel

  // stage x_0
  {
    float p0 = xbase[0], p1 = xbase[NPIX], p2 = xbase[2 * NPIX], p3 = xbase[3 * NPIX];
    ushort4 pk;
    pk.x = f2bf(p0); pk.y = f2bf(p1); pk.z = f2bf(p2); pk.w = f2bf(p3);
    *(ushort4*)&xs[nl * LDS_STRIDE + cb] = pk;
  }
  __syncthreads();

  const int fro = l15 * LDS_STRIDE + quad * 8;  // A-frag element offset

  for (int t = 0; t < TT; ++t) {
    // prefetch x_{t+1} early (consumed after the bottom barrier)
    const bool pf = (t + 1 < T);
    float q0, q1, q2, q3;
    if (pf) {
      const float* p = xbase + (size_t)(t + 1) * C * NPIX;
      q0 = p[0]; q1 = p[NPIX]; q2 = p[2 * NPIX]; q3 = p[3 * NPIX];
    }

    // at phase switch, fold W_sum = W_ih + W_hh into fih (registers only)
    if (t == T) {
      #pragma unroll
      for (int nt = 0; nt < 4; ++nt)
        #pragma unroll
        for (int kt = 0; kt < 4; ++kt) {
          short8 a = fih[nt][kt], b = fhh[nt][kt];
          #pragma unroll
          for (int j = 0; j < 8; ++j)
            a[j] = (short)f2bf(bf2f((unsigned short)a[j]) + bf2f((unsigned short)b[j]));
          fih[nt][kt] = a;
        }
    }

    // gates = x@Wih^T + h@Whh^T + b   (AR phase: h@(Wih+Whh)^T + b)
    f32x4 acc[4];
    #pragma unroll
    for (int nt = 0; nt < 4; ++nt)
      acc[nt] = (f32x4){bias[nt], bias[nt], bias[nt], bias[nt]};

    if (t < T) {
      #pragma unroll
      for (int kt = 0; kt < 4; ++kt) {
        short8 ax = *(const short8*)&xs[fro + kt * 32];
        short8 ah = *(const short8*)&hs[fro + kt * 32];
        #pragma unroll
        for (int nt = 0; nt < 4; ++nt) {
          acc[nt] = __builtin_amdgcn_mfma_f32_16x16x32_bf16(ax, fih[nt][kt], acc[nt], 0, 0, 0);
          acc[nt] = __builtin_amdgcn_mfma_f32_16x16x32_bf16(ah, fhh[nt][kt], acc[nt], 0, 0, 0);
        }
      }
    } else {
      #pragma unroll
      for (int kt = 0; kt < 4; ++kt) {
        short8 ah = *(const short8*)&hs[fro + kt * 32];
        #pragma unroll
        for (int nt = 0; nt < 4; ++nt)
          acc[nt] = __builtin_amdgcn_mfma_f32_16x16x32_bf16(ah, fih[nt][kt], acc[nt], 0, 0, 0);
      }
    }

    // activations + state update (all in-register; acc[0..3] = i,f,g,o)
    float hv[4];
    #pragma unroll
    for (int r = 0; r < 4; ++r) {
      float ig = fast_sigmoid(acc[0][r]);
      float fg = fast_sigmoid(acc[1][r]);
      float gg = fast_tanh(acc[2][r]);
      float og = fast_sigmoid(acc[3][r]);
      c[r] = fg * c[r] + ig * gg;
      hv[r] = og * fast_tanh(c[r]);
    }

    // stream h to output (fp32, nontemporal: 239 MB total, don't thrash L2)
    {
      float* ob = out + (size_t)(n0 + quad * 4) * (TT * H) + (size_t)t * H + hid;
      #pragma unroll
      for (int r = 0; r < 4; ++r)
        __builtin_nontemporal_store(hv[r], ob + (size_t)r * (TT * H));
    }

    __syncthreads();  // all A-frag reads of this step are done

    if (pf) {
      ushort4 pk;
      pk.x = f2bf(q0); pk.y = f2bf(q1); pk.z = f2bf(q2); pk.w = f2bf(q3);
      *(ushort4*)&xs[nl * LDS_STRIDE + cb] = pk;
    }
    #pragma unroll
    for (int r = 0; r < 4; ++r)
      hs[(quad * 4 + r) * LDS_STRIDE + hid] = f2bf(hv[r]);

    __syncthreads();  // h_lds/x_lds ready for next step
  }
}

extern "C" void kernel_launch(void* const* d_in, const int* in_sizes, int n_in,
                              void* d_out, int out_size, void* d_ws, size_t ws_size,
                              hipStream_t stream) {
  (void)in_sizes; (void)n_in; (void)d_ws; (void)ws_size; (void)out_size;
  const float* img = (const float*)d_in[0];
  // d_in[1] = mask (unused by reference forward)
  const float* wih = (const float*)d_in[2];
  const float* whh = (const float*)d_in[3];
  const float* bih = (const float*)d_in[4];
  const float* bhh = (const float*)d_in[5];
  // d_in[6] = gp_affected_timesteps (static = 5, baked into EXTRA)
  float* out = (float*)d_out;

  lstm_persistent<<<NPIX / 16, 512, 0, stream>>>(img, wih, whh, bih, bhh, out);
}